// Round 7
// baseline (267.455 us; speedup 1.0000x reference)
//
#include <hip/hip_runtime.h>
#include <stdint.h>

typedef unsigned short ushort_t;
typedef __attribute__((ext_vector_type(8))) short short8;
typedef __attribute__((ext_vector_type(4))) float floatx4;
typedef __attribute__((ext_vector_type(4))) float floatv4;
typedef __attribute__((ext_vector_type(4))) unsigned short ushortv4;

// B=64, I=128, J=512, H=16, D=64, QD=512, KVD=256, HID=1024

__device__ __forceinline__ ushort_t f2bf(float x) {
    union { float f; unsigned u; } v; v.f = x;
    unsigned r = v.u + 0x7fffu + ((v.u >> 16) & 1u);   // RNE
    return (ushort_t)(r >> 16);
}

// async global->LDS, 16B per lane; LDS dst = wave-uniform base + lane*16
__device__ __forceinline__ void gl_lds16(const ushort_t* g, ushort_t* l) {
    __builtin_amdgcn_global_load_lds(
        (const __attribute__((address_space(1))) void*)g,
        (__attribute__((address_space(3))) void*)l, 16, 0, 0);
}

// ---------------- fused prep: casts + TILED weight transposes ----------------
// blocks [0,4096): q cast | [4096,12288): kv cast |
// [12288,12416): Wq 64x64-tile transpose | [12416,12544): Wkv | [12544,12672): Wo
__global__ __launch_bounds__(256) void prep_kernel(
    const float* __restrict__ q, const float* __restrict__ kv,
    const float* __restrict__ Wq, const float* __restrict__ Wkv,
    const float* __restrict__ Wo,
    ushort_t* __restrict__ qA, ushort_t* __restrict__ kvA,
    ushort_t* __restrict__ WqT, ushort_t* __restrict__ WkvT,
    ushort_t* __restrict__ WoT)
{
    __shared__ ushort_t tileS[64 * 68];
    const int bid = blockIdx.x;
    const int tid = threadIdx.x;
    if (bid < 4096) {                       // q: 4,194,304 floats -> bf16
        int t = bid * 256 + tid;
        floatv4 v = ((const floatv4*)q)[t];
        ushortv4 o;
        o[0] = f2bf(v[0]); o[1] = f2bf(v[1]); o[2] = f2bf(v[2]); o[3] = f2bf(v[3]);
        ((ushortv4*)qA)[t] = o;
        return;
    }
    if (bid < 12288) {                      // kv: 8,388,608 floats -> bf16
        int t = (bid - 4096) * 256 + tid;
        floatv4 v = ((const floatv4*)kv)[t];
        ushortv4 o;
        o[0] = f2bf(v[0]); o[1] = f2bf(v[1]); o[2] = f2bf(v[2]); o[3] = f2bf(v[3]);
        ((ushortv4*)kvA)[t] = o;
        return;
    }
    // ---- 64x64 tiled transpose: dst[n*K+k] = src[k*N+n] * scale ----
    const float* src; ushort_t* dst; int K, N, kt, nt; float scale = 1.0f;
    if (bid < 12416)      { int tl = bid - 12288; src = Wq;  dst = WqT;  K = 512;  N = 1024; kt = tl >> 4; nt = tl & 15; scale = 0.125f; }
    else if (bid < 12544) { int tl = bid - 12416; src = Wkv; dst = WkvT; K = 256;  N = 2048; kt = tl >> 5; nt = tl & 31; }
    else                  { int tl = bid - 12544; src = Wo;  dst = WoT;  K = 1024; N = 512;  kt = tl >> 3; nt = tl & 7;  }
#pragma unroll
    for (int t = 0; t < 4; t++) {           // coalesced float4 reads
        int e = t * 256 + tid;
        int row = e >> 4, c4 = e & 15;
        floatv4 v = *(const floatv4*)&src[(size_t)(kt * 64 + row) * N + nt * 64 + c4 * 4];
        ushortv4 o;
        o[0] = f2bf(v[0] * scale); o[1] = f2bf(v[1] * scale);
        o[2] = f2bf(v[2] * scale); o[3] = f2bf(v[3] * scale);
        *(ushortv4*)&tileS[row * 68 + c4 * 4] = o;
    }
    __syncthreads();
#pragma unroll
    for (int t = 0; t < 4; t++) {           // coalesced 8B bf16 writes
        int e = t * 256 + tid;
        int orow = e >> 4, c4 = e & 15;
        ushortv4 o;
#pragma unroll
        for (int e2 = 0; e2 < 4; e2++) o[e2] = tileS[(c4 * 4 + e2) * 68 + orow];
        *(ushortv4*)&dst[(size_t)(nt * 64 + orow) * K + kt * 64 + c4 * 4] = o;
    }
}

// ---------------- GEMM: C = A (MxK) * Bt^T (m97-style), for o-proj ----------
__global__ __launch_bounds__(256, 3) void gemm_bt_kernel(
    const ushort_t* __restrict__ A, const ushort_t* __restrict__ Bt,
    int M, int N, int K, int gx, int gy, int emode,
    ushort_t* __restrict__ out_a,
    float* __restrict__ out_f, const float* __restrict__ bias)
{
    __shared__ ushort_t smem[16896];          // sA|sB: 2 x 128x64 (32KB); sT: 128x132
    ushort_t* sA = smem;
    ushort_t* sB = smem + 8192;
    ushort_t* sT = smem;

    const int bid  = blockIdx.x;
    const int xcd  = bid & 7;
    const int slot = bid >> 3;
    const int band = gy >> 3;
    const int by   = xcd * band + slot % band;
    const int bx   = slot / band;

    const int tid  = threadIdx.x;
    const int lane = tid & 63;
    const int w    = tid >> 6;
    const int quad = lane >> 4;
    const int l15  = lane & 15;
    const int wr   = w >> 1, wc = w & 1;
    const int m0 = by * 128;
    const int n0 = bx * 128;

    const int rsub = lane >> 3;
    const int c8   = lane & 7;
    const int wrow = w * 32;

    floatx4 acc[4][4];
#pragma unroll
    for (int i = 0; i < 4; i++)
#pragma unroll
        for (int j = 0; j < 4; j++) acc[i][j] = (floatx4){0.f, 0.f, 0.f, 0.f};

    for (int k0 = 0; k0 < K; k0 += 64) {
        __syncthreads();
#pragma unroll
        for (int t = 0; t < 4; t++) {
            int rg = wrow + t * 8;
            gl_lds16(&A[(size_t)(m0 + rg + rsub) * K + k0 + c8 * 8], &sA[rg * 64]);
            gl_lds16(&Bt[(size_t)(n0 + rg + rsub) * K + k0 + c8 * 8], &sB[rg * 64]);
        }
        __syncthreads();
#pragma unroll
        for (int ks = 0; ks < 64; ks += 32) {
            short8 af[4], bf[4];
#pragma unroll
            for (int i = 0; i < 4; i++)
                af[i] = *(const short8*)&sA[(wr * 64 + i * 16 + l15) * 64 + ks + quad * 8];
#pragma unroll
            for (int j = 0; j < 4; j++)
                bf[j] = *(const short8*)&sB[(wc * 64 + j * 16 + l15) * 64 + ks + quad * 8];
#pragma unroll
            for (int i = 0; i < 4; i++)
#pragma unroll
                for (int j = 0; j < 4; j++)
                    acc[i][j] = __builtin_amdgcn_mfma_f32_16x16x32_bf16(
                        af[i], bf[j], acc[i][j], 0, 0, 0);
        }
    }

    // C layout: row = quad*4+r, col = lane&15 (verified m89/m91)
    if (emode == 2) {
#pragma unroll
        for (int i = 0; i < 4; i++)
#pragma unroll
            for (int j = 0; j < 4; j++)
#pragma unroll
                for (int r = 0; r < 4; r++) {
                    int grow = m0 + wr * 64 + i * 16 + quad * 4 + r;
                    int gcol = n0 + wc * 64 + j * 16 + l15;
                    out_f[(size_t)grow * N + gcol] = acc[i][j][r] + bias[gcol];
                }
        return;
    }

    __syncthreads();
#pragma unroll
    for (int i = 0; i < 4; i++)
#pragma unroll
        for (int j = 0; j < 4; j++)
#pragma unroll
            for (int r = 0; r < 4; r++) {
                int row = wr * 64 + i * 16 + quad * 4 + r;
                int col = wc * 64 + j * 16 + l15;
                sT[row * 132 + col] = f2bf(acc[i][j][r]);
            }
    __syncthreads();
#pragma unroll
    for (int it = 0; it < 8; it++) {
        int idx = it * 256 + tid;
        int row = idx >> 4, chunk = idx & 15;
        short8 v = *(const short8*)&sT[row * 132 + chunk * 8];
        *(short8*)&out_a[(size_t)(m0 + row) * 1024 + n0 + chunk * 8] = v;
    }
}

// ------- fused Q-projection + KV-projection + flash attention (v12) ---------
// grid = B*H = 1024 blocks, 512 threads (8 waves), 69.6 KB LDS -> 2 blocks/CU.
// v12 = v10 (the 99.0 us best; v11's swz64 reverted) + proj re-tile (2,2):
// LDS-BW model: ~4.4 GB LDS traffic ~= 64 us at the 69 TB/s ceiling = the
// ~65% of kernel time that TLP (r4), prefetch (r5) and conflict-shuffling
// (r6) couldn't touch. Dominant term = proj A-reads: each wave re-read the
// full 64x256 kv chunk (32 KB) for only 16 output cols. Now wave (jg=w>>2,
// ng=w&3) covers 32 j-rows x 32 n-cols: A-reads halve (16 KB/wave/chunk,
// -1.05 GB total), same MFMA count, wf doubles to 64 VGPRs (watch spill).
__global__ __launch_bounds__(512, 4) void fattn_kernel(
    const ushort_t* __restrict__ QA,   // qA  (b*128+i, 512) bf16
    const ushort_t* __restrict__ WQ,   // WqT (1024, 512) bf16, scale folded
    const ushort_t* __restrict__ KV,   // kvA (b*512+j, 256) bf16
    const ushort_t* __restrict__ W,    // WkvT (2048, 256) bf16
    ushort_t* __restrict__ O)          // (b*128+i, 1024)
{
    __shared__ ushort_t smem[34816];        // 69,632 B total
    ushort_t* sKV = smem;                   // main: 64x256 linear+swz (32 KB)
    ushort_t* sKc = smem + 16384;           // main: 64x72   ( 9.2 KB)
    ushort_t* sVt = smem + 20992;           // main: 64x72   ( 9.2 KB)
    ushort_t* sP  = smem + 25600;           // main: 8x16x72 (18.4 KB)
    ushort_t* sQ  = smem;                   // phase0: 128x128 linear+swz (32 KB)
    ushort_t* sW  = smem + 16384;           // phase0: 64x128 linear+swz (16 KB)

    // b-locality swizzle: xcd = bid&7 owns b in {8*xcd .. 8*xcd+7}
    const int bid  = blockIdx.x;
    const int xcd  = bid & 7;
    const int slot = bid >> 3;              // 0..127
    const int b = xcd * 8 + (slot & 7);
    const int h = slot >> 3;

    const int tid  = threadIdx.x;
    const int lane = tid & 63, w = tid >> 6;
    const int quad = lane >> 4, l15 = lane & 15;
    const int swz  = (l15 & 7) << 3;        // read-side XOR for sKV/sQ/sW (16B gran)
    const int jg   = w >> 2, ng = w & 3;    // proj tile: 32 j-rows x 32 n-cols

    ushort_t* sp = &sP[w * 1152];           // 16 x 72 per wave (private)

    // staging lane geometry
    const int rq = lane >> 4;               // sub-row 0..3 (4-row calls, 256B rows)
    const int gq = l15 * 8;                 // granule col, ushort units
    const int rh = lane >> 5;               // sub-row 0..1 (2-row calls, 512B rows)
    const int gk = (lane & 31) * 8;

    // ================= phase 0: q-projection for this (b,h) =================
    const ushort_t* qb = &QA[(size_t)b * 128 * 512];
    const ushort_t* wq = &WQ[(size_t)h * 64 * 512];
    floatx4 qacc[4];
#pragma unroll
    for (int nt = 0; nt < 4; nt++) qacc[nt] = (floatx4){0.f, 0.f, 0.f, 0.f};

    for (int kc = 0; kc < 4; kc++) {
        if (kc) __syncthreads();            // prev sub-chunk reads done
#pragma unroll
        for (int t = 0; t < 4; t++) {       // sQ: 16 rows/wave, 4 rows/call
            int rb = w * 16 + t * 4;        // wave-uniform LDS row base
            int srow = rb + rq;
            int scol = kc * 128 + (gq ^ ((srow & 7) << 3));
            gl_lds16(&qb[(size_t)srow * 512 + scol], &sQ[rb * 128]);
        }
#pragma unroll
        for (int t = 0; t < 2; t++) {       // sW: 8 rows/wave, 4 rows/call
            int rb = w * 8 + t * 4;
            int srow = rb + rq;
            int scol = kc * 128 + (gq ^ ((srow & 7) << 3));
            gl_lds16(&wq[(size_t)srow * 512 + scol], &sW[rb * 128]);
        }
        __syncthreads();                    // staging visible (vmcnt(0) implied)
#pragma unroll
        for (int ks = 0; ks < 4; ks++) {
            short8 af = *(const short8*)&sQ[(w * 16 + l15) * 128 + ((ks * 32 + quad * 8) ^ swz)];
#pragma unroll
            for (int nt = 0; nt < 4; nt++) {
                short8 bfr = *(const short8*)&sW[(nt * 16 + l15) * 128 + ((ks * 32 + quad * 8) ^ swz)];
                qacc[nt] = __builtin_amdgcn_mfma_f32_16x16x32_bf16(af, bfr, qacc[nt], 0, 0, 0);
            }
        }
    }
    __syncthreads();                        // all phase-0 LDS reads done

    const ushort_t* kvb = &KV[(size_t)b * 512 * 256];
    // issue kv chunk-0 staging NOW: covered by qh remap + wf loads below.
    // wave w stages its rows 8w..8w+7; 2 rows (1 KB) per call.
#define STAGE_KV(CH)                                                          \
    {                                                                         \
        _Pragma("unroll")                                                     \
        for (int t = 0; t < 4; t++) {                                         \
            int rloc = 8 * w + 2 * t;       /* wave-uniform LDS row base */   \
            int srow = rloc + rh;                                             \
            int scol = gk ^ ((srow & 7) << 3);                                \
            gl_lds16(&kvb[(size_t)((CH) * 64 + srow) * 256 + scol],           \
                     &sKV[rloc * 256]);                                       \
        }                                                                     \
    }
    STAGE_KV(0);

    // qh C-frags -> per-wave sp -> A-frags (lane remap through LDS)
#pragma unroll
    for (int nt = 0; nt < 4; nt++)
#pragma unroll
        for (int r = 0; r < 4; r++)
            sp[(quad * 4 + r) * 72 + nt * 16 + l15] = f2bf(qacc[nt][r]);
    short8 aq0 = *(const short8*)&sp[l15 * 72 + quad * 8];
    short8 aq1 = *(const short8*)&sp[l15 * 72 + 32 + quad * 8];

    // ---- W (kv) fragments in registers: wave (jg,ng) owns 32 n-cols ----
    short8 wf[2][8];
#pragma unroll
    for (int nt = 0; nt < 2; nt++) {
        int nb = ng * 32 + nt * 16 + l15;   // 0..127 across ng,nt
        int grow = (nb < 64) ? (h * 64 + nb) : (1024 + h * 64 + (nb - 64));
        const ushort_t* wp = &W[(size_t)grow * 256 + quad * 8];
#pragma unroll
        for (int ks = 0; ks < 8; ks++)
            wf[nt][ks] = *(const short8*)(wp + ks * 32);
    }

    float lsum[4];
    floatx4 acc_o[4];
#pragma unroll
    for (int r = 0; r < 4; r++) lsum[r] = 0.f;
#pragma unroll
    for (int dt = 0; dt < 4; dt++) acc_o[dt] = (floatx4){0.f, 0.f, 0.f, 0.f};

    // ========================= main loop: 8 j-chunks ========================
    for (int ch = 0; ch < 8; ch++) {
        __syncthreads();                    // B1: vmcnt(0) drains prefetch; staging visible

        // ---- projection: pacc[jt][nt] = kv rows (jg*32+jt*16..) @ W cols
        //      (ng*32+nt*16..), K=256; A-reads halved vs (4,1) tiling ----
        floatx4 pacc[2][2];
#pragma unroll
        for (int jt = 0; jt < 2; jt++)
#pragma unroll
            for (int nt = 0; nt < 2; nt++) pacc[jt][nt] = (floatx4){0.f, 0.f, 0.f, 0.f};
#pragma unroll
        for (int ks = 0; ks < 8; ks++) {
            short8 af[2];
#pragma unroll
            for (int jt = 0; jt < 2; jt++)
                af[jt] = *(const short8*)&sKV[(jg * 32 + jt * 16 + l15) * 256 + ((ks * 32 + quad * 8) ^ swz)];
#pragma unroll
            for (int jt = 0; jt < 2; jt++)
#pragma unroll
                for (int nt = 0; nt < 2; nt++)
                    pacc[jt][nt] = __builtin_amdgcn_mfma_f32_16x16x32_bf16(
                        af[jt], wf[nt][ks], pacc[jt][nt], 0, 0, 0);
        }

        // ---- write Kc / Vc^T to LDS (C layout: row j = quad*4+r, col = l15) --
        if (ng < 2) {                       // K cols ng*32 .. ng*32+31
#pragma unroll
            for (int jt = 0; jt < 2; jt++)
#pragma unroll
                for (int nt = 0; nt < 2; nt++)
#pragma unroll
                    for (int r = 0; r < 4; r++)
                        sKc[(jg * 32 + jt * 16 + quad * 4 + r) * 72 + ng * 32 + nt * 16 + l15]
                            = f2bf(pacc[jt][nt][r]);
        } else {                            // V cols (ng-2)*32 .. +31, transposed
            int db = (ng - 2) * 32;
#pragma unroll
            for (int jt = 0; jt < 2; jt++)
#pragma unroll
                for (int nt = 0; nt < 2; nt++) {
                    ushortv4 p;
#pragma unroll
                    for (int r = 0; r < 4; r++) p[r] = f2bf(pacc[jt][nt][r]);
                    *(ushortv4*)&sVt[(db + nt * 16 + l15) * 72 + jg * 32 + jt * 16 + quad * 4] = p;
                }
        }
        __syncthreads();                    // B2: Kc/Vt visible; ALL proj sKV reads done

        // ---- issue next chunk's staging: hides under S+exp+PV ----
        if (ch < 7) STAGE_KV(ch + 1);

        // ---- S = Q * Kc^T (16 x 64), then P = exp(S) (no max needed) ----
#pragma unroll
        for (int jt = 0; jt < 4; jt++) {
            const ushort_t* kp = &sKc[(jt * 16 + l15) * 72 + quad * 8];
            short8 bk0 = *(const short8*)kp;
            short8 bk1 = *(const short8*)(kp + 32);
            floatx4 a = (floatx4){0.f, 0.f, 0.f, 0.f};
            a = __builtin_amdgcn_mfma_f32_16x16x32_bf16(aq0, bk0, a, 0, 0, 0);
            a = __builtin_amdgcn_mfma_f32_16x16x32_bf16(aq1, bk1, a, 0, 0, 0);
            ushortv4 pk;
#pragma unroll
            for (int r = 0; r < 4; r++) {
                float p = __expf(a[r]);
                lsum[r] += p;
                pk[r] = f2bf(p);
            }
#pragma unroll
            for (int r = 0; r < 4; r++)
                sp[(quad * 4 + r) * 72 + jt * 16 + l15] = pk[r];
        }

        // ---- O += P * V  (K = 64 j), per-wave private sp: no barrier ----
#pragma unroll
        for (int kk = 0; kk < 2; kk++) {
            short8 ap = *(const short8*)&sp[l15 * 72 + kk * 32 + quad * 8];
#pragma unroll
            for (int dt = 0; dt < 4; dt++) {
                short8 bv = *(const short8*)&sVt[(dt * 16 + l15) * 72 + kk * 32 + quad * 8];
                acc_o[dt] = __builtin_amdgcn_mfma_f32_16x16x32_bf16(ap, bv, acc_o[dt], 0, 0, 0);
            }
        }
    }

    // ---- final row-sum reduction (within 16-lane l15 groups) + write ----
#pragma unroll
    for (int r = 0; r < 4; r++) {
        float s = lsum[r];
#pragma unroll
        for (int off = 1; off < 16; off <<= 1) s += __shfl_xor(s, off);
        float inv = 1.0f / s;
        size_t rowo = (size_t)(b * 128 + w * 16 + quad * 4 + r) * 1024 + h * 64;
#pragma unroll
        for (int dt = 0; dt < 4; dt++)
            O[rowo + dt * 16 + l15] = f2bf(acc_o[dt][r] * inv);
    }
#undef STAGE_KV
}

// ---------------- launch ----------------
extern "C" void kernel_launch(void* const* d_in, const int* in_sizes, int n_in,
                              void* d_out, int out_size, void* d_ws, size_t ws_size,
                              hipStream_t stream) {
    const float* q   = (const float*)d_in[0];   // (64,128,512)
    const float* kv  = (const float*)d_in[1];   // (64,512,256)
    const float* Wq  = (const float*)d_in[2];   // (512,1024)
    const float* Wkv = (const float*)d_in[3];   // (256,2048)
    const float* Wo  = (const float*)d_in[4];   // (1024,512)
    const float* bo  = (const float*)d_in[5];   // (512,)
    float* out = (float*)d_out;

    char* ws = (char*)d_ws;
    ushort_t* qA    = (ushort_t*)(ws + 0);          //  8 MB  (8192 x 512)
    ushort_t* kvA   = (ushort_t*)(ws + 8388608);    // 16 MB  (32768 x 256)
    ushort_t* WqT   = (ushort_t*)(ws + 25165824);   //  1 MB  (1024 x 512)
    ushort_t* WkvT  = (ushort_t*)(ws + 26214400);   //  1 MB  (2048 x 256)
    ushort_t* WoT   = (ushort_t*)(ws + 27262976);   //  1 MB  (512 x 1024)
    ushort_t* attnO = (ushort_t*)(ws + 45088768);   // 16 MB  (8192 x 1024)

    // fused prep: casts + tiled weight transposes, one launch
    hipLaunchKernelGGL(prep_kernel, dim3(12672), dim3(256), 0, stream,
                       q, kv, Wq, Wkv, Wo, qA, kvA, WqT, WkvT, WoT);

    // fused q-proj + kv-proj + attention ((2,2) proj tiling, halved LDS reads)
    hipLaunchKernelGGL(fattn_kernel, dim3(1024), dim3(512), 0, stream,
                       qA, WqT, kvA, WkvT, attnO);

    // out = attnO @ Wo + bo   [gx=4, gy=64]
    hipLaunchKernelGGL(gemm_bt_kernel, dim3(256), dim3(256), 0, stream,
                       attnO, WoT, 8192, 512, 1024, 4, 64, 2, (ushort_t*)nullptr,
                       out, bo);
}

// Round 8
// 229.343 us; speedup vs baseline: 1.1662x; 1.1662x over previous
//
#include <hip/hip_runtime.h>
#include <stdint.h>

typedef unsigned short ushort_t;
typedef __attribute__((ext_vector_type(8))) short short8;
typedef __attribute__((ext_vector_type(4))) float floatx4;
typedef __attribute__((ext_vector_type(4))) float floatv4;
typedef __attribute__((ext_vector_type(4))) unsigned short ushortv4;

// B=64, I=128, J=512, H=16, D=64, QD=512, KVD=256, HID=1024

__device__ __forceinline__ ushort_t f2bf(float x) {
    union { float f; unsigned u; } v; v.f = x;
    unsigned r = v.u + 0x7fffu + ((v.u >> 16) & 1u);   // RNE
    return (ushort_t)(r >> 16);
}

// async global->LDS, 16B per lane; LDS dst = wave-uniform base + lane*16
__device__ __forceinline__ void gl_lds16(const ushort_t* g, ushort_t* l) {
    __builtin_amdgcn_global_load_lds(
        (const __attribute__((address_space(1))) void*)g,
        (__attribute__((address_space(3))) void*)l, 16, 0, 0);
}

// ---------------- fused prep: casts + TILED weight transposes ----------------
// blocks [0,4096): q cast | [4096,12288): kv cast |
// [12288,12416): Wq 64x64-tile transpose | [12416,12544): Wkv | [12544,12672): Wo
__global__ __launch_bounds__(256) void prep_kernel(
    const float* __restrict__ q, const float* __restrict__ kv,
    const float* __restrict__ Wq, const float* __restrict__ Wkv,
    const float* __restrict__ Wo,
    ushort_t* __restrict__ qA, ushort_t* __restrict__ kvA,
    ushort_t* __restrict__ WqT, ushort_t* __restrict__ WkvT,
    ushort_t* __restrict__ WoT)
{
    __shared__ ushort_t tileS[64 * 68];
    const int bid = blockIdx.x;
    const int tid = threadIdx.x;
    if (bid < 4096) {                       // q: 4,194,304 floats -> bf16
        int t = bid * 256 + tid;
        floatv4 v = ((const floatv4*)q)[t];
        ushortv4 o;
        o[0] = f2bf(v[0]); o[1] = f2bf(v[1]); o[2] = f2bf(v[2]); o[3] = f2bf(v[3]);
        ((ushortv4*)qA)[t] = o;
        return;
    }
    if (bid < 12288) {                      // kv: 8,388,608 floats -> bf16
        int t = (bid - 4096) * 256 + tid;
        floatv4 v = ((const floatv4*)kv)[t];
        ushortv4 o;
        o[0] = f2bf(v[0]); o[1] = f2bf(v[1]); o[2] = f2bf(v[2]); o[3] = f2bf(v[3]);
        ((ushortv4*)kvA)[t] = o;
        return;
    }
    // ---- 64x64 tiled transpose: dst[n*K+k] = src[k*N+n] * scale ----
    const float* src; ushort_t* dst; int K, N, kt, nt; float scale = 1.0f;
    if (bid < 12416)      { int tl = bid - 12288; src = Wq;  dst = WqT;  K = 512;  N = 1024; kt = tl >> 4; nt = tl & 15; scale = 0.125f; }
    else if (bid < 12544) { int tl = bid - 12416; src = Wkv; dst = WkvT; K = 256;  N = 2048; kt = tl >> 5; nt = tl & 31; }
    else                  { int tl = bid - 12544; src = Wo;  dst = WoT;  K = 1024; N = 512;  kt = tl >> 3; nt = tl & 7;  }
#pragma unroll
    for (int t = 0; t < 4; t++) {           // coalesced float4 reads
        int e = t * 256 + tid;
        int row = e >> 4, c4 = e & 15;
        floatv4 v = *(const floatv4*)&src[(size_t)(kt * 64 + row) * N + nt * 64 + c4 * 4];
        ushortv4 o;
        o[0] = f2bf(v[0] * scale); o[1] = f2bf(v[1] * scale);
        o[2] = f2bf(v[2] * scale); o[3] = f2bf(v[3] * scale);
        *(ushortv4*)&tileS[row * 68 + c4 * 4] = o;
    }
    __syncthreads();
#pragma unroll
    for (int t = 0; t < 4; t++) {           // coalesced 8B bf16 writes
        int e = t * 256 + tid;
        int orow = e >> 4, c4 = e & 15;
        ushortv4 o;
#pragma unroll
        for (int e2 = 0; e2 < 4; e2++) o[e2] = tileS[(c4 * 4 + e2) * 68 + orow];
        *(ushortv4*)&dst[(size_t)(nt * 64 + orow) * K + kt * 64 + c4 * 4] = o;
    }
}

// ---------------- GEMM: C = A (MxK) * Bt^T (m97-style), for o-proj ----------
__global__ __launch_bounds__(256, 3) void gemm_bt_kernel(
    const ushort_t* __restrict__ A, const ushort_t* __restrict__ Bt,
    int M, int N, int K, int gx, int gy, int emode,
    ushort_t* __restrict__ out_a,
    float* __restrict__ out_f, const float* __restrict__ bias)
{
    __shared__ ushort_t smem[16896];          // sA|sB: 2 x 128x64 (32KB); sT: 128x132
    ushort_t* sA = smem;
    ushort_t* sB = smem + 8192;
    ushort_t* sT = smem;

    const int bid  = blockIdx.x;
    const int xcd  = bid & 7;
    const int slot = bid >> 3;
    const int band = gy >> 3;
    const int by   = xcd * band + slot % band;
    const int bx   = slot / band;

    const int tid  = threadIdx.x;
    const int lane = tid & 63;
    const int w    = tid >> 6;
    const int quad = lane >> 4;
    const int l15  = lane & 15;
    const int wr   = w >> 1, wc = w & 1;
    const int m0 = by * 128;
    const int n0 = bx * 128;

    const int rsub = lane >> 3;
    const int c8   = lane & 7;
    const int wrow = w * 32;

    floatx4 acc[4][4];
#pragma unroll
    for (int i = 0; i < 4; i++)
#pragma unroll
        for (int j = 0; j < 4; j++) acc[i][j] = (floatx4){0.f, 0.f, 0.f, 0.f};

    for (int k0 = 0; k0 < K; k0 += 64) {
        __syncthreads();
#pragma unroll
        for (int t = 0; t < 4; t++) {
            int rg = wrow + t * 8;
            gl_lds16(&A[(size_t)(m0 + rg + rsub) * K + k0 + c8 * 8], &sA[rg * 64]);
            gl_lds16(&Bt[(size_t)(n0 + rg + rsub) * K + k0 + c8 * 8], &sB[rg * 64]);
        }
        __syncthreads();
#pragma unroll
        for (int ks = 0; ks < 64; ks += 32) {
            short8 af[4], bf[4];
#pragma unroll
            for (int i = 0; i < 4; i++)
                af[i] = *(const short8*)&sA[(wr * 64 + i * 16 + l15) * 64 + ks + quad * 8];
#pragma unroll
            for (int j = 0; j < 4; j++)
                bf[j] = *(const short8*)&sB[(wc * 64 + j * 16 + l15) * 64 + ks + quad * 8];
#pragma unroll
            for (int i = 0; i < 4; i++)
#pragma unroll
                for (int j = 0; j < 4; j++)
                    acc[i][j] = __builtin_amdgcn_mfma_f32_16x16x32_bf16(
                        af[i], bf[j], acc[i][j], 0, 0, 0);
        }
    }

    // C layout: row = quad*4+r, col = lane&15 (verified m89/m91)
    if (emode == 2) {
#pragma unroll
        for (int i = 0; i < 4; i++)
#pragma unroll
            for (int j = 0; j < 4; j++)
#pragma unroll
                for (int r = 0; r < 4; r++) {
                    int grow = m0 + wr * 64 + i * 16 + quad * 4 + r;
                    int gcol = n0 + wc * 64 + j * 16 + l15;
                    out_f[(size_t)grow * N + gcol] = acc[i][j][r] + bias[gcol];
                }
        return;
    }

    __syncthreads();
#pragma unroll
    for (int i = 0; i < 4; i++)
#pragma unroll
        for (int j = 0; j < 4; j++)
#pragma unroll
            for (int r = 0; r < 4; r++) {
                int row = wr * 64 + i * 16 + quad * 4 + r;
                int col = wc * 64 + j * 16 + l15;
                sT[row * 132 + col] = f2bf(acc[i][j][r]);
            }
    __syncthreads();
#pragma unroll
    for (int it = 0; it < 8; it++) {
        int idx = it * 256 + tid;
        int row = idx >> 4, chunk = idx & 15;
        short8 v = *(const short8*)&sT[row * 132 + chunk * 8];
        *(short8*)&out_a[(size_t)(m0 + row) * 1024 + n0 + chunk * 8] = v;
    }
}

// ------- fused Q-projection + KV-projection + flash attention (v13) ---------
// grid = B*H = 1024 blocks, 512 threads (8 waves), 69.6 KB LDS -> 2 blocks/CU.
// v13 = v12 ((2,2) proj tiling: halves proj LDS A-reads, the dominant term of
// the saturated LDS pipe) with __launch_bounds__(512, 2).
// Empirical law from r3/r4/r7: hipcc clamps VGPRs to ~256/arg and SPILLS the
// overflow to scratch (arg=6 -> 40 VGPR, arg=4 -> 64 VGPR; r7's (2,2) needs
// ~125-131 live -> spilled at 64: FETCH 268MB/WRITE 98MB scratch signature).
// arg=2 -> target 128 VGPR: fits the (2,2) live set; 128 VGPR still admits
// 4 waves/SIMD = 16 waves/CU = the 2 blocks/CU that LDS already caps, so no
// occupancy loss; and the regime is LDS-throughput-bound anyway (r4/r5).
__global__ __launch_bounds__(512, 2) void fattn_kernel(
    const ushort_t* __restrict__ QA,   // qA  (b*128+i, 512) bf16
    const ushort_t* __restrict__ WQ,   // WqT (1024, 512) bf16, scale folded
    const ushort_t* __restrict__ KV,   // kvA (b*512+j, 256) bf16
    const ushort_t* __restrict__ W,    // WkvT (2048, 256) bf16
    ushort_t* __restrict__ O)          // (b*128+i, 1024)
{
    __shared__ ushort_t smem[34816];        // 69,632 B total
    ushort_t* sKV = smem;                   // main: 64x256 linear+swz (32 KB)
    ushort_t* sKc = smem + 16384;           // main: 64x72   ( 9.2 KB)
    ushort_t* sVt = smem + 20992;           // main: 64x72   ( 9.2 KB)
    ushort_t* sP  = smem + 25600;           // main: 8x16x72 (18.4 KB)
    ushort_t* sQ  = smem;                   // phase0: 128x128 linear+swz (32 KB)
    ushort_t* sW  = smem + 16384;           // phase0: 64x128 linear+swz (16 KB)

    // b-locality swizzle: xcd = bid&7 owns b in {8*xcd .. 8*xcd+7}
    const int bid  = blockIdx.x;
    const int xcd  = bid & 7;
    const int slot = bid >> 3;              // 0..127
    const int b = xcd * 8 + (slot & 7);
    const int h = slot >> 3;

    const int tid  = threadIdx.x;
    const int lane = tid & 63, w = tid >> 6;
    const int quad = lane >> 4, l15 = lane & 15;
    const int swz  = (l15 & 7) << 3;        // read-side XOR for sKV/sQ/sW (16B gran)
    const int jg   = w >> 2, ng = w & 3;    // proj tile: 32 j-rows x 32 n-cols

    ushort_t* sp = &sP[w * 1152];           // 16 x 72 per wave (private)

    // staging lane geometry
    const int rq = lane >> 4;               // sub-row 0..3 (4-row calls, 256B rows)
    const int gq = l15 * 8;                 // granule col, ushort units
    const int rh = lane >> 5;               // sub-row 0..1 (2-row calls, 512B rows)
    const int gk = (lane & 31) * 8;

    // ================= phase 0: q-projection for this (b,h) =================
    const ushort_t* qb = &QA[(size_t)b * 128 * 512];
    const ushort_t* wq = &WQ[(size_t)h * 64 * 512];
    floatx4 qacc[4];
#pragma unroll
    for (int nt = 0; nt < 4; nt++) qacc[nt] = (floatx4){0.f, 0.f, 0.f, 0.f};

    for (int kc = 0; kc < 4; kc++) {
        if (kc) __syncthreads();            // prev sub-chunk reads done
#pragma unroll
        for (int t = 0; t < 4; t++) {       // sQ: 16 rows/wave, 4 rows/call
            int rb = w * 16 + t * 4;        // wave-uniform LDS row base
            int srow = rb + rq;
            int scol = kc * 128 + (gq ^ ((srow & 7) << 3));
            gl_lds16(&qb[(size_t)srow * 512 + scol], &sQ[rb * 128]);
        }
#pragma unroll
        for (int t = 0; t < 2; t++) {       // sW: 8 rows/wave, 4 rows/call
            int rb = w * 8 + t * 4;
            int srow = rb + rq;
            int scol = kc * 128 + (gq ^ ((srow & 7) << 3));
            gl_lds16(&wq[(size_t)srow * 512 + scol], &sW[rb * 128]);
        }
        __syncthreads();                    // staging visible (vmcnt(0) implied)
#pragma unroll
        for (int ks = 0; ks < 4; ks++) {
            short8 af = *(const short8*)&sQ[(w * 16 + l15) * 128 + ((ks * 32 + quad * 8) ^ swz)];
#pragma unroll
            for (int nt = 0; nt < 4; nt++) {
                short8 bfr = *(const short8*)&sW[(nt * 16 + l15) * 128 + ((ks * 32 + quad * 8) ^ swz)];
                qacc[nt] = __builtin_amdgcn_mfma_f32_16x16x32_bf16(af, bfr, qacc[nt], 0, 0, 0);
            }
        }
    }
    __syncthreads();                        // all phase-0 LDS reads done

    const ushort_t* kvb = &KV[(size_t)b * 512 * 256];
    // issue kv chunk-0 staging NOW: covered by qh remap + wf loads below.
    // wave w stages its rows 8w..8w+7; 2 rows (1 KB) per call.
#define STAGE_KV(CH)                                                          \
    {                                                                         \
        _Pragma("unroll")                                                     \
        for (int t = 0; t < 4; t++) {                                         \
            int rloc = 8 * w + 2 * t;       /* wave-uniform LDS row base */   \
            int srow = rloc + rh;                                             \
            int scol = gk ^ ((srow & 7) << 3);                                \
            gl_lds16(&kvb[(size_t)((CH) * 64 + srow) * 256 + scol],           \
                     &sKV[rloc * 256]);                                       \
        }                                                                     \
    }
    STAGE_KV(0);

    // qh C-frags -> per-wave sp -> A-frags (lane remap through LDS)
#pragma unroll
    for (int nt = 0; nt < 4; nt++)
#pragma unroll
        for (int r = 0; r < 4; r++)
            sp[(quad * 4 + r) * 72 + nt * 16 + l15] = f2bf(qacc[nt][r]);
    short8 aq0 = *(const short8*)&sp[l15 * 72 + quad * 8];
    short8 aq1 = *(const short8*)&sp[l15 * 72 + 32 + quad * 8];

    // ---- W (kv) fragments in registers: wave (jg,ng) owns 32 n-cols ----
    short8 wf[2][8];
#pragma unroll
    for (int nt = 0; nt < 2; nt++) {
        int nb = ng * 32 + nt * 16 + l15;   // 0..127 across ng,nt
        int grow = (nb < 64) ? (h * 64 + nb) : (1024 + h * 64 + (nb - 64));
        const ushort_t* wp = &W[(size_t)grow * 256 + quad * 8];
#pragma unroll
        for (int ks = 0; ks < 8; ks++)
            wf[nt][ks] = *(const short8*)(wp + ks * 32);
    }

    float lsum[4];
    floatx4 acc_o[4];
#pragma unroll
    for (int r = 0; r < 4; r++) lsum[r] = 0.f;
#pragma unroll
    for (int dt = 0; dt < 4; dt++) acc_o[dt] = (floatx4){0.f, 0.f, 0.f, 0.f};

    // ========================= main loop: 8 j-chunks ========================
    for (int ch = 0; ch < 8; ch++) {
        __syncthreads();                    // B1: vmcnt(0) drains prefetch; staging visible

        // ---- projection: pacc[jt][nt] = kv rows (jg*32+jt*16..) @ W cols
        //      (ng*32+nt*16..), K=256; A-reads halved vs (4,1) tiling ----
        floatx4 pacc[2][2];
#pragma unroll
        for (int jt = 0; jt < 2; jt++)
#pragma unroll
            for (int nt = 0; nt < 2; nt++) pacc[jt][nt] = (floatx4){0.f, 0.f, 0.f, 0.f};
#pragma unroll
        for (int ks = 0; ks < 8; ks++) {
            short8 af[2];
#pragma unroll
            for (int jt = 0; jt < 2; jt++)
                af[jt] = *(const short8*)&sKV[(jg * 32 + jt * 16 + l15) * 256 + ((ks * 32 + quad * 8) ^ swz)];
#pragma unroll
            for (int jt = 0; jt < 2; jt++)
#pragma unroll
                for (int nt = 0; nt < 2; nt++)
                    pacc[jt][nt] = __builtin_amdgcn_mfma_f32_16x16x32_bf16(
                        af[jt], wf[nt][ks], pacc[jt][nt], 0, 0, 0);
        }

        // ---- write Kc / Vc^T to LDS (C layout: row j = quad*4+r, col = l15) --
        if (ng < 2) {                       // K cols ng*32 .. ng*32+31
#pragma unroll
            for (int jt = 0; jt < 2; jt++)
#pragma unroll
                for (int nt = 0; nt < 2; nt++)
#pragma unroll
                    for (int r = 0; r < 4; r++)
                        sKc[(jg * 32 + jt * 16 + quad * 4 + r) * 72 + ng * 32 + nt * 16 + l15]
                            = f2bf(pacc[jt][nt][r]);
        } else {                            // V cols (ng-2)*32 .. +31, transposed
            int db = (ng - 2) * 32;
#pragma unroll
            for (int jt = 0; jt < 2; jt++)
#pragma unroll
                for (int nt = 0; nt < 2; nt++) {
                    ushortv4 p;
#pragma unroll
                    for (int r = 0; r < 4; r++) p[r] = f2bf(pacc[jt][nt][r]);
                    *(ushortv4*)&sVt[(db + nt * 16 + l15) * 72 + jg * 32 + jt * 16 + quad * 4] = p;
                }
        }
        __syncthreads();                    // B2: Kc/Vt visible; ALL proj sKV reads done

        // ---- issue next chunk's staging: hides under S+exp+PV ----
        if (ch < 7) STAGE_KV(ch + 1);

        // ---- S = Q * Kc^T (16 x 64), then P = exp(S) (no max needed) ----
#pragma unroll
        for (int jt = 0; jt < 4; jt++) {
            const ushort_t* kp = &sKc[(jt * 16 + l15) * 72 + quad * 8];
            short8 bk0 = *(const short8*)kp;
            short8 bk1 = *(const short8*)(kp + 32);
            floatx4 a = (floatx4){0.f, 0.f, 0.f, 0.f};
            a = __builtin_amdgcn_mfma_f32_16x16x32_bf16(aq0, bk0, a, 0, 0, 0);
            a = __builtin_amdgcn_mfma_f32_16x16x32_bf16(aq1, bk1, a, 0, 0, 0);
            ushortv4 pk;
#pragma unroll
            for (int r = 0; r < 4; r++) {
                float p = __expf(a[r]);
                lsum[r] += p;
                pk[r] = f2bf(p);
            }
#pragma unroll
            for (int r = 0; r < 4; r++)
                sp[(quad * 4 + r) * 72 + jt * 16 + l15] = pk[r];
        }

        // ---- O += P * V  (K = 64 j), per-wave private sp: no barrier ----
#pragma unroll
        for (int kk = 0; kk < 2; kk++) {
            short8 ap = *(const short8*)&sp[l15 * 72 + kk * 32 + quad * 8];
#pragma unroll
            for (int dt = 0; dt < 4; dt++) {
                short8 bv = *(const short8*)&sVt[(dt * 16 + l15) * 72 + kk * 32 + quad * 8];
                acc_o[dt] = __builtin_amdgcn_mfma_f32_16x16x32_bf16(ap, bv, acc_o[dt], 0, 0, 0);
            }
        }
    }

    // ---- final row-sum reduction (within 16-lane l15 groups) + write ----
#pragma unroll
    for (int r = 0; r < 4; r++) {
        float s = lsum[r];
#pragma unroll
        for (int off = 1; off < 16; off <<= 1) s += __shfl_xor(s, off);
        float inv = 1.0f / s;
        size_t rowo = (size_t)(b * 128 + w * 16 + quad * 4 + r) * 1024 + h * 64;
#pragma unroll
        for (int dt = 0; dt < 4; dt++)
            O[rowo + dt * 16 + l15] = f2bf(acc_o[dt][r] * inv);
    }
#undef STAGE_KV
}

// ---------------- launch ----------------
extern "C" void kernel_launch(void* const* d_in, const int* in_sizes, int n_in,
                              void* d_out, int out_size, void* d_ws, size_t ws_size,
                              hipStream_t stream) {
    const float* q   = (const float*)d_in[0];   // (64,128,512)
    const float* kv  = (const float*)d_in[1];   // (64,512,256)
    const float* Wq  = (const float*)d_in[2];   // (512,1024)
    const float* Wkv = (const float*)d_in[3];   // (256,2048)
    const float* Wo  = (const float*)d_in[4];   // (1024,512)
    const float* bo  = (const float*)d_in[5];   // (512,)
    float* out = (float*)d_out;

    char* ws = (char*)d_ws;
    ushort_t* qA    = (ushort_t*)(ws + 0);          //  8 MB  (8192 x 512)
    ushort_t* kvA   = (ushort_t*)(ws + 8388608);    // 16 MB  (32768 x 256)
    ushort_t* WqT   = (ushort_t*)(ws + 25165824);   //  1 MB  (1024 x 512)
    ushort_t* WkvT  = (ushort_t*)(ws + 26214400);   //  1 MB  (2048 x 256)
    ushort_t* WoT   = (ushort_t*)(ws + 27262976);   //  1 MB  (512 x 1024)
    ushort_t* attnO = (ushort_t*)(ws + 45088768);   // 16 MB  (8192 x 1024)

    // fused prep: casts + tiled weight transposes, one launch
    hipLaunchKernelGGL(prep_kernel, dim3(12672), dim3(256), 0, stream,
                       q, kv, Wq, Wkv, Wo, qA, kvA, WqT, WkvT, WoT);

    // fused q-proj + kv-proj + attention ((2,2) tiling + 128-VGPR budget)
    hipLaunchKernelGGL(fattn_kernel, dim3(1024), dim3(512), 0, stream,
                       qA, WqT, kvA, WkvT, attnO);

    // out = attnO @ Wo + bo   [gx=4, gy=64]
    hipLaunchKernelGGL(gemm_bt_kernel, dim3(256), dim3(256), 0, stream,
                       attnO, WoT, 8192, 512, 1024, 4, 64, 2, (ushort_t*)nullptr,
                       out, bo);
}

// Round 11
// 203.737 us; speedup vs baseline: 1.3127x; 1.1257x over previous
//
#include <hip/hip_runtime.h>
#include <stdint.h>

typedef unsigned short ushort_t;
typedef __attribute__((ext_vector_type(8))) short short8;
typedef __attribute__((ext_vector_type(4))) float floatx4;
typedef __attribute__((ext_vector_type(4))) float floatv4;
typedef __attribute__((ext_vector_type(4))) unsigned short ushortv4;

// B=64, I=128, J=512, H=16, D=64, QD=512, KVD=256, HID=1024

__device__ __forceinline__ ushort_t f2bf(float x) {
    union { float f; unsigned u; } v; v.f = x;
    unsigned r = v.u + 0x7fffu + ((v.u >> 16) & 1u);   // RNE
    return (ushort_t)(r >> 16);
}

// async global->LDS, 16B per lane; LDS dst = wave-uniform base + lane*16
__device__ __forceinline__ void gl_lds16(const ushort_t* g, ushort_t* l) {
    __builtin_amdgcn_global_load_lds(
        (const __attribute__((address_space(1))) void*)g,
        (__attribute__((address_space(3))) void*)l, 16, 0, 0);
}

// ---------------- fused prep: casts + TILED weight transposes ----------------
// blocks [0,4096): q cast | [4096,12288): kv cast |
// [12288,12416): Wq 64x64-tile transpose | [12416,12544): Wkv | [12544,12672): Wo
__global__ __launch_bounds__(256) void prep_kernel(
    const float* __restrict__ q, const float* __restrict__ kv,
    const float* __restrict__ Wq, const float* __restrict__ Wkv,
    const float* __restrict__ Wo,
    ushort_t* __restrict__ qA, ushort_t* __restrict__ kvA,
    ushort_t* __restrict__ WqT, ushort_t* __restrict__ WkvT,
    ushort_t* __restrict__ WoT)
{
    __shared__ ushort_t tileS[64 * 68];
    const int bid = blockIdx.x;
    const int tid = threadIdx.x;
    if (bid < 4096) {                       // q: 4,194,304 floats -> bf16
        int t = bid * 256 + tid;
        floatv4 v = ((const floatv4*)q)[t];
        ushortv4 o;
        o[0] = f2bf(v[0]); o[1] = f2bf(v[1]); o[2] = f2bf(v[2]); o[3] = f2bf(v[3]);
        ((ushortv4*)qA)[t] = o;
        return;
    }
    if (bid < 12288) {                      // kv: 8,388,608 floats -> bf16
        int t = (bid - 4096) * 256 + tid;
        floatv4 v = ((const floatv4*)kv)[t];
        ushortv4 o;
        o[0] = f2bf(v[0]); o[1] = f2bf(v[1]); o[2] = f2bf(v[2]); o[3] = f2bf(v[3]);
        ((ushortv4*)kvA)[t] = o;
        return;
    }
    // ---- 64x64 tiled transpose: dst[n*K+k] = src[k*N+n] * scale ----
    const float* src; ushort_t* dst; int K, N, kt, nt; float scale = 1.0f;
    if (bid < 12416)      { int tl = bid - 12288; src = Wq;  dst = WqT;  K = 512;  N = 1024; kt = tl >> 4; nt = tl & 15; scale = 0.125f; }
    else if (bid < 12544) { int tl = bid - 12416; src = Wkv; dst = WkvT; K = 256;  N = 2048; kt = tl >> 5; nt = tl & 31; }
    else                  { int tl = bid - 12544; src = Wo;  dst = WoT;  K = 1024; N = 512;  kt = tl >> 3; nt = tl & 7;  }
#pragma unroll
    for (int t = 0; t < 4; t++) {           // coalesced float4 reads
        int e = t * 256 + tid;
        int row = e >> 4, c4 = e & 15;
        floatv4 v = *(const floatv4*)&src[(size_t)(kt * 64 + row) * N + nt * 64 + c4 * 4];
        ushortv4 o;
        o[0] = f2bf(v[0] * scale); o[1] = f2bf(v[1] * scale);
        o[2] = f2bf(v[2] * scale); o[3] = f2bf(v[3] * scale);
        *(ushortv4*)&tileS[row * 68 + c4 * 4] = o;
    }
    __syncthreads();
#pragma unroll
    for (int t = 0; t < 4; t++) {           // coalesced 8B bf16 writes
        int e = t * 256 + tid;
        int orow = e >> 4, c4 = e & 15;
        ushortv4 o;
#pragma unroll
        for (int e2 = 0; e2 < 4; e2++) o[e2] = tileS[(c4 * 4 + e2) * 68 + orow];
        *(ushortv4*)&dst[(size_t)(nt * 64 + orow) * K + kt * 64 + c4 * 4] = o;
    }
}

// ------ GEMM: out = A (8192x1024) * Bt^T (512x1024) + bias, 64x64 tiles -----
// v16: retiled from 128x128 (grid 256 = 1 block/CU, the degenerate m97 config
// measured at ~123 TF / ~70us) to 64x64 -> grid 1024 = 4 blocks/CU (m97's
// proven operating point). Same verified staging / fragment / C-layout
// patterns, re-parameterized. LDS 16KB/block (4x16=64KB/CU fits).
// XCD swizzle: by = xcd*16 + slot%16 keeps all 8 bx-blocks sharing an
// A-panel on one XCD (panel L2-hot); B (1MB) is L2-resident everywhere.
__global__ __launch_bounds__(256, 4) void gemm_bt_kernel(
    const ushort_t* __restrict__ A, const ushort_t* __restrict__ Bt,
    int M, int N, int K,
    float* __restrict__ out_f, const float* __restrict__ bias)
{
    __shared__ ushort_t smem[8192];           // sA|sB: 2 x 64x64 (16KB)
    ushort_t* sA = smem;
    ushort_t* sB = smem + 4096;

    const int bid  = blockIdx.x;              // 0..1023
    const int xcd  = bid & 7;
    const int slot = bid >> 3;                // 0..127
    const int by   = xcd * 16 + (slot & 15);  // 0..127 (M/64)
    const int bx   = slot >> 4;               // 0..7   (N/64)

    const int tid  = threadIdx.x;
    const int lane = tid & 63;
    const int w    = tid >> 6;                // 4 waves
    const int quad = lane >> 4;
    const int l15  = lane & 15;
    const int wr   = w >> 1, wc = w & 1;      // 2x2 wave grid, 32x32 each
    const int m0 = by * 64;
    const int n0 = bx * 64;

    const int rsub = lane >> 3;               // 0..7 (8 rows per gl_lds16 call)
    const int c8   = lane & 7;

    floatx4 acc[2][2];
#pragma unroll
    for (int i = 0; i < 2; i++)
#pragma unroll
        for (int j = 0; j < 2; j++) acc[i][j] = (floatx4){0.f, 0.f, 0.f, 0.f};

    for (int k0 = 0; k0 < K; k0 += 64) {
        __syncthreads();                      // prev iteration's reads done
#pragma unroll
        for (int t = 0; t < 2; t++) {         // wave w stages rows w*16..w*16+15
            int rg = w * 16 + t * 8;
            gl_lds16(&A[(size_t)(m0 + rg + rsub) * K + k0 + c8 * 8], &sA[rg * 64]);
            gl_lds16(&Bt[(size_t)(n0 + rg + rsub) * K + k0 + c8 * 8], &sB[rg * 64]);
        }
        __syncthreads();                      // staging visible (vmcnt(0) implied)
#pragma unroll
        for (int ks = 0; ks < 64; ks += 32) {
            short8 af[2], bf[2];
#pragma unroll
            for (int i = 0; i < 2; i++)
                af[i] = *(const short8*)&sA[(wr * 32 + i * 16 + l15) * 64 + ks + quad * 8];
#pragma unroll
            for (int j = 0; j < 2; j++)
                bf[j] = *(const short8*)&sB[(wc * 32 + j * 16 + l15) * 64 + ks + quad * 8];
#pragma unroll
            for (int i = 0; i < 2; i++)
#pragma unroll
                for (int j = 0; j < 2; j++)
                    acc[i][j] = __builtin_amdgcn_mfma_f32_16x16x32_bf16(
                        af[i], bf[j], acc[i][j], 0, 0, 0);
        }
    }

    // C layout: row = quad*4+r, col = lane&15 (verified m89/m91)
#pragma unroll
    for (int i = 0; i < 2; i++)
#pragma unroll
        for (int j = 0; j < 2; j++)
#pragma unroll
            for (int r = 0; r < 4; r++) {
                int grow = m0 + wr * 32 + i * 16 + quad * 4 + r;
                int gcol = n0 + wc * 32 + j * 16 + l15;
                out_f[(size_t)grow * N + gcol] = acc[i][j][r] + bias[gcol];
            }
}

// ------- fused Q-projection + KV-projection + flash attention (v10) ---------
// grid = B*H = 1024 blocks, 512 threads (8 waves), 69.6 KB LDS -> 2 blocks/CU.
// VERBATIM the verified 99.08us round-5 kernel. (v14/v15's global-direct
// phase 0 failed correctness twice with no identifiable mechanism -- family
// abandoned; staged phase 0 retained.)
__global__ __launch_bounds__(512, 4) void fattn_kernel(
    const ushort_t* __restrict__ QA,   // qA  (b*128+i, 512) bf16
    const ushort_t* __restrict__ WQ,   // WqT (1024, 512) bf16, scale folded
    const ushort_t* __restrict__ KV,   // kvA (b*512+j, 256) bf16
    const ushort_t* __restrict__ W,    // WkvT (2048, 256) bf16
    ushort_t* __restrict__ O)          // (b*128+i, 1024)
{
    __shared__ ushort_t smem[34816];        // 69,632 B total
    ushort_t* sKV = smem;                   // main: 64x256 linear+swz (32 KB)
    ushort_t* sKc = smem + 16384;           // main: 64x72   ( 9.2 KB)
    ushort_t* sVt = smem + 20992;           // main: 64x72   ( 9.2 KB)
    ushort_t* sP  = smem + 25600;           // main: 8x16x72 (18.4 KB)
    ushort_t* sQ  = smem;                   // phase0: 128x128 linear+swz (32 KB)
    ushort_t* sW  = smem + 16384;           // phase0: 64x128 linear+swz (16 KB)

    // b-locality swizzle: xcd = bid&7 owns b in {8*xcd .. 8*xcd+7}
    const int bid  = blockIdx.x;
    const int xcd  = bid & 7;
    const int slot = bid >> 3;              // 0..127
    const int b = xcd * 8 + (slot & 7);
    const int h = slot >> 3;

    const int tid  = threadIdx.x;
    const int lane = tid & 63, w = tid >> 6;
    const int quad = lane >> 4, l15 = lane & 15;
    const int swz  = (l15 & 7) << 3;        // read-side XOR, ushort units (16B gran)

    ushort_t* sp = &sP[w * 1152];           // 16 x 72 per wave (private)

    // staging lane geometry
    const int rq = lane >> 4;               // sub-row 0..3 (4-row calls, 256B rows)
    const int gq = l15 * 8;                 // granule col, ushort units
    const int rh = lane >> 5;               // sub-row 0..1 (2-row calls, 512B rows)
    const int gk = (lane & 31) * 8;

    // ================= phase 0: q-projection for this (b,h) =================
    const ushort_t* qb = &QA[(size_t)b * 128 * 512];
    const ushort_t* wq = &WQ[(size_t)h * 64 * 512];
    floatx4 qacc[4];
#pragma unroll
    for (int nt = 0; nt < 4; nt++) qacc[nt] = (floatx4){0.f, 0.f, 0.f, 0.f};

    for (int kc = 0; kc < 4; kc++) {
        if (kc) __syncthreads();            // prev sub-chunk reads done
#pragma unroll
        for (int t = 0; t < 4; t++) {       // sQ: 16 rows/wave, 4 rows/call
            int rb = w * 16 + t * 4;        // wave-uniform LDS row base
            int srow = rb + rq;
            int scol = kc * 128 + (gq ^ ((srow & 7) << 3));
            gl_lds16(&qb[(size_t)srow * 512 + scol], &sQ[rb * 128]);
        }
#pragma unroll
        for (int t = 0; t < 2; t++) {       // sW: 8 rows/wave, 4 rows/call
            int rb = w * 8 + t * 4;
            int srow = rb + rq;
            int scol = kc * 128 + (gq ^ ((srow & 7) << 3));
            gl_lds16(&wq[(size_t)srow * 512 + scol], &sW[rb * 128]);
        }
        __syncthreads();                    // staging visible (vmcnt(0) implied)
#pragma unroll
        for (int ks = 0; ks < 4; ks++) {
            short8 af = *(const short8*)&sQ[(w * 16 + l15) * 128 + ((ks * 32 + quad * 8) ^ swz)];
#pragma unroll
            for (int nt = 0; nt < 4; nt++) {
                short8 bfr = *(const short8*)&sW[(nt * 16 + l15) * 128 + ((ks * 32 + quad * 8) ^ swz)];
                qacc[nt] = __builtin_amdgcn_mfma_f32_16x16x32_bf16(af, bfr, qacc[nt], 0, 0, 0);
            }
        }
    }
    __syncthreads();                        // all phase-0 LDS reads done

    const ushort_t* kvb = &KV[(size_t)b * 512 * 256];
    // issue kv chunk-0 staging NOW: covered by qh remap + wf loads below.
    // wave w stages its rows 8w..8w+7; 2 rows (1 KB) per call.
#define STAGE_KV(CH)                                                          \
    {                                                                         \
        _Pragma("unroll")                                                     \
        for (int t = 0; t < 4; t++) {                                         \
            int rloc = 8 * w + 2 * t;       /* wave-uniform LDS row base */   \
            int srow = rloc + rh;                                             \
            int scol = gk ^ ((srow & 7) << 3);                                \
            gl_lds16(&kvb[(size_t)((CH) * 64 + srow) * 256 + scol],           \
                     &sKV[rloc * 256]);                                       \
        }                                                                     \
    }
    STAGE_KV(0);

    // qh C-frags -> per-wave sp -> A-frags (lane remap through LDS)
#pragma unroll
    for (int nt = 0; nt < 4; nt++)
#pragma unroll
        for (int r = 0; r < 4; r++)
            sp[(quad * 4 + r) * 72 + nt * 16 + l15] = f2bf(qacc[nt][r]);
    short8 aq0 = *(const short8*)&sp[l15 * 72 + quad * 8];
    short8 aq1 = *(const short8*)&sp[l15 * 72 + 32 + quad * 8];

    // ---- W (kv) fragments in registers: wave w owns proj n-tile w ----
    short8 wf[8];
    {
        int n = w * 16 + l15;
        int grow = (n < 64) ? (h * 64 + n) : (1024 + h * 64 + (n - 64));
        const ushort_t* wp = &W[(size_t)grow * 256 + quad * 8];
#pragma unroll
        for (int ks = 0; ks < 8; ks++)
            wf[ks] = *(const short8*)(wp + ks * 32);
    }

    float lsum[4];
    floatx4 acc_o[4];
#pragma unroll
    for (int r = 0; r < 4; r++) lsum[r] = 0.f;
#pragma unroll
    for (int dt = 0; dt < 4; dt++) acc_o[dt] = (floatx4){0.f, 0.f, 0.f, 0.f};

    // ========================= main loop: 8 j-chunks ========================
    for (int ch = 0; ch < 8; ch++) {
        __syncthreads();                    // B1: vmcnt(0) drains prefetch; staging visible

        // ---- projection: pacc[jt] = kv_chunk(jt) @ W n-tile w, K=256 ----
        floatx4 pacc[4];
#pragma unroll
        for (int jt = 0; jt < 4; jt++) pacc[jt] = (floatx4){0.f, 0.f, 0.f, 0.f};
#pragma unroll
        for (int ks = 0; ks < 8; ks++) {
            short8 af[4];
#pragma unroll
            for (int jt = 0; jt < 4; jt++)
                af[jt] = *(const short8*)&sKV[(jt * 16 + l15) * 256 + ((ks * 32 + quad * 8) ^ swz)];
#pragma unroll
            for (int jt = 0; jt < 4; jt++)
                pacc[jt] = __builtin_amdgcn_mfma_f32_16x16x32_bf16(
                    af[jt], wf[ks], pacc[jt], 0, 0, 0);
        }

        // ---- write Kc / Vc^T to LDS (C layout: row j = quad*4+r, col = l15) --
        if (w < 4) {
            int d = w * 16 + l15;
#pragma unroll
            for (int jt = 0; jt < 4; jt++)
#pragma unroll
                for (int r = 0; r < 4; r++)
                    sKc[(jt * 16 + quad * 4 + r) * 72 + d] = f2bf(pacc[jt][r]);
        } else {
            int d = (w - 4) * 16 + l15;
#pragma unroll
            for (int jt = 0; jt < 4; jt++) {
                ushortv4 p;
#pragma unroll
                for (int r = 0; r < 4; r++) p[r] = f2bf(pacc[jt][r]);
                *(ushortv4*)&sVt[d * 72 + jt * 16 + quad * 4] = p;
            }
        }
        __syncthreads();                    // B2: Kc/Vt visible; ALL proj sKV reads done

        // ---- issue next chunk's staging: hides under S+exp+PV ----
        if (ch < 7) STAGE_KV(ch + 1);

        // ---- S = Q * Kc^T (16 x 64), then P = exp(S) (no max needed) ----
#pragma unroll
        for (int jt = 0; jt < 4; jt++) {
            const ushort_t* kp = &sKc[(jt * 16 + l15) * 72 + quad * 8];
            short8 bk0 = *(const short8*)kp;
            short8 bk1 = *(const short8*)(kp + 32);
            floatx4 a = (floatx4){0.f, 0.f, 0.f, 0.f};
            a = __builtin_amdgcn_mfma_f32_16x16x32_bf16(aq0, bk0, a, 0, 0, 0);
            a = __builtin_amdgcn_mfma_f32_16x16x32_bf16(aq1, bk1, a, 0, 0, 0);
            ushortv4 pk;
#pragma unroll
            for (int r = 0; r < 4; r++) {
                float p = __expf(a[r]);
                lsum[r] += p;
                pk[r] = f2bf(p);
            }
#pragma unroll
            for (int r = 0; r < 4; r++)
                sp[(quad * 4 + r) * 72 + jt * 16 + l15] = pk[r];
        }

        // ---- O += P * V  (K = 64 j), per-wave private sp: no barrier ----
#pragma unroll
        for (int kk = 0; kk < 2; kk++) {
            short8 ap = *(const short8*)&sp[l15 * 72 + kk * 32 + quad * 8];
#pragma unroll
            for (int dt = 0; dt < 4; dt++) {
                short8 bv = *(const short8*)&sVt[(dt * 16 + l15) * 72 + kk * 32 + quad * 8];
                acc_o[dt] = __builtin_amdgcn_mfma_f32_16x16x32_bf16(ap, bv, acc_o[dt], 0, 0, 0);
            }
        }
    }

    // ---- final row-sum reduction (within 16-lane l15 groups) + write ----
#pragma unroll
    for (int r = 0; r < 4; r++) {
        float s = lsum[r];
#pragma unroll
        for (int off = 1; off < 16; off <<= 1) s += __shfl_xor(s, off);
        float inv = 1.0f / s;
        size_t rowo = (size_t)(b * 128 + w * 16 + quad * 4 + r) * 1024 + h * 64;
#pragma unroll
        for (int dt = 0; dt < 4; dt++)
            O[rowo + dt * 16 + l15] = f2bf(acc_o[dt][r] * inv);
    }
#undef STAGE_KV
}

// ---------------- launch ----------------
extern "C" void kernel_launch(void* const* d_in, const int* in_sizes, int n_in,
                              void* d_out, int out_size, void* d_ws, size_t ws_size,
                              hipStream_t stream) {
    const float* q   = (const float*)d_in[0];   // (64,128,512)
    const float* kv  = (const float*)d_in[1];   // (64,512,256)
    const float* Wq  = (const float*)d_in[2];   // (512,1024)
    const float* Wkv = (const float*)d_in[3];   // (256,2048)
    const float* Wo  = (const float*)d_in[4];   // (1024,512)
    const float* bo  = (const float*)d_in[5];   // (512,)
    float* out = (float*)d_out;

    char* ws = (char*)d_ws;
    ushort_t* qA    = (ushort_t*)(ws + 0);          //  8 MB  (8192 x 512)
    ushort_t* kvA   = (ushort_t*)(ws + 8388608);    // 16 MB  (32768 x 256)
    ushort_t* WqT   = (ushort_t*)(ws + 25165824);   //  1 MB  (1024 x 512)
    ushort_t* WkvT  = (ushort_t*)(ws + 26214400);   //  1 MB  (2048 x 256)
    ushort_t* WoT   = (ushort_t*)(ws + 27262976);   //  1 MB  (512 x 1024)
    ushort_t* attnO = (ushort_t*)(ws + 45088768);   // 16 MB  (8192 x 1024)

    // fused prep: casts + tiled weight transposes, one launch
    hipLaunchKernelGGL(prep_kernel, dim3(12672), dim3(256), 0, stream,
                       q, kv, Wq, Wkv, Wo, qA, kvA, WqT, WkvT, WoT);

    // fused q-proj + kv-proj + attention (v10 verbatim, verified 99 us)
    hipLaunchKernelGGL(fattn_kernel, dim3(1024), dim3(512), 0, stream,
                       qA, WqT, kvA, WkvT, attnO);

    // out = attnO @ Wo + bo  -- 64x64 tiles, 1024 blocks = 4 blocks/CU
    hipLaunchKernelGGL(gemm_bt_kernel, dim3(1024), dim3(256), 0, stream,
                       attnO, WoT, 8192, 512, 1024, out, bo);
}

// Round 12
// 202.247 us; speedup vs baseline: 1.3224x; 1.0074x over previous
//
#include <hip/hip_runtime.h>
#include <stdint.h>

typedef unsigned short ushort_t;
typedef __attribute__((ext_vector_type(8))) short short8;
typedef __attribute__((ext_vector_type(4))) float floatx4;
typedef __attribute__((ext_vector_type(4))) float floatv4;
typedef __attribute__((ext_vector_type(4))) unsigned short ushortv4;

// B=64, I=128, J=512, H=16, D=64, QD=512, KVD=256, HID=1024

__device__ __forceinline__ ushort_t f2bf(float x) {
    union { float f; unsigned u; } v; v.f = x;
    unsigned r = v.u + 0x7fffu + ((v.u >> 16) & 1u);   // RNE
    return (ushort_t)(r >> 16);
}

// async global->LDS, 16B per lane; LDS dst = wave-uniform base + lane*16
__device__ __forceinline__ void gl_lds16(const ushort_t* g, ushort_t* l) {
    __builtin_amdgcn_global_load_lds(
        (const __attribute__((address_space(1))) void*)g,
        (__attribute__((address_space(3))) void*)l, 16, 0, 0);
}

// ---------------- fused prep: casts + TILED weight transposes ----------------
// v17: casts are 8-floats/thread (2x float4 load -> one 16B bf16x8 store).
// blocks [0,2048): q cast | [2048,6144): kv cast |
// [6144,6272): Wq 64x64-tile transpose | [6272,6400): Wkv | [6400,6528): Wo
__global__ __launch_bounds__(256) void prep_kernel(
    const float* __restrict__ q, const float* __restrict__ kv,
    const float* __restrict__ Wq, const float* __restrict__ Wkv,
    const float* __restrict__ Wo,
    ushort_t* __restrict__ qA, ushort_t* __restrict__ kvA,
    ushort_t* __restrict__ WqT, ushort_t* __restrict__ WkvT,
    ushort_t* __restrict__ WoT)
{
    __shared__ ushort_t tileS[64 * 68];
    const int bid = blockIdx.x;
    const int tid = threadIdx.x;
    if (bid < 6144) {                       // q then kv: f32 -> bf16, 8/thread
        const float* src = (bid < 2048) ? q : kv;
        ushort_t* dst    = (bid < 2048) ? qA : kvA;
        size_t t = (size_t)(bid < 2048 ? bid : bid - 2048) * 256 + tid;
        const float* s = src + t * 8;
        floatv4 v0 = *(const floatv4*)s;
        floatv4 v1 = *(const floatv4*)(s + 4);
        short8 o;
        o[0] = (short)f2bf(v0[0]); o[1] = (short)f2bf(v0[1]);
        o[2] = (short)f2bf(v0[2]); o[3] = (short)f2bf(v0[3]);
        o[4] = (short)f2bf(v1[0]); o[5] = (short)f2bf(v1[1]);
        o[6] = (short)f2bf(v1[2]); o[7] = (short)f2bf(v1[3]);
        *(short8*)&dst[t * 8] = o;
        return;
    }
    // ---- 64x64 tiled transpose: dst[n*K+k] = src[k*N+n] * scale ----
    const float* src; ushort_t* dst; int K, N, kt, nt; float scale = 1.0f;
    if (bid < 6272)      { int tl = bid - 6144; src = Wq;  dst = WqT;  K = 512;  N = 1024; kt = tl >> 4; nt = tl & 15; scale = 0.125f; }
    else if (bid < 6400) { int tl = bid - 6272; src = Wkv; dst = WkvT; K = 256;  N = 2048; kt = tl >> 5; nt = tl & 31; }
    else                 { int tl = bid - 6400; src = Wo;  dst = WoT;  K = 1024; N = 512;  kt = tl >> 3; nt = tl & 7;  }
#pragma unroll
    for (int t = 0; t < 4; t++) {           // coalesced float4 reads
        int e = t * 256 + tid;
        int row = e >> 4, c4 = e & 15;
        floatv4 v = *(const floatv4*)&src[(size_t)(kt * 64 + row) * N + nt * 64 + c4 * 4];
        ushortv4 o;
        o[0] = f2bf(v[0] * scale); o[1] = f2bf(v[1] * scale);
        o[2] = f2bf(v[2] * scale); o[3] = f2bf(v[3] * scale);
        *(ushortv4*)&tileS[row * 68 + c4 * 4] = o;
    }
    __syncthreads();
#pragma unroll
    for (int t = 0; t < 4; t++) {           // coalesced 8B bf16 writes
        int e = t * 256 + tid;
        int orow = e >> 4, c4 = e & 15;
        ushortv4 o;
#pragma unroll
        for (int e2 = 0; e2 < 4; e2++) o[e2] = tileS[(c4 * 4 + e2) * 68 + orow];
        *(ushortv4*)&dst[(size_t)(nt * 64 + orow) * K + kt * 64 + c4 * 4] = o;
    }
}

// ------ GEMM: out = A (8192x1024) * Bt^T (512x1024) + bias, 64x64 tiles -----
// 1024 blocks = 4 blocks/CU (r11: verified, total -4.9us vs 128^2 tiles).
__global__ __launch_bounds__(256, 4) void gemm_bt_kernel(
    const ushort_t* __restrict__ A, const ushort_t* __restrict__ Bt,
    int M, int N, int K,
    float* __restrict__ out_f, const float* __restrict__ bias)
{
    __shared__ ushort_t smem[8192];           // sA|sB: 2 x 64x64 (16KB)
    ushort_t* sA = smem;
    ushort_t* sB = smem + 4096;

    const int bid  = blockIdx.x;              // 0..1023
    const int xcd  = bid & 7;
    const int slot = bid >> 3;                // 0..127
    const int by   = xcd * 16 + (slot & 15);  // 0..127 (M/64)
    const int bx   = slot >> 4;               // 0..7   (N/64)

    const int tid  = threadIdx.x;
    const int lane = tid & 63;
    const int w    = tid >> 6;                // 4 waves
    const int quad = lane >> 4;
    const int l15  = lane & 15;
    const int wr   = w >> 1, wc = w & 1;      // 2x2 wave grid, 32x32 each
    const int m0 = by * 64;
    const int n0 = bx * 64;

    const int rsub = lane >> 3;               // 0..7 (8 rows per gl_lds16 call)
    const int c8   = lane & 7;

    floatx4 acc[2][2];
#pragma unroll
    for (int i = 0; i < 2; i++)
#pragma unroll
        for (int j = 0; j < 2; j++) acc[i][j] = (floatx4){0.f, 0.f, 0.f, 0.f};

    for (int k0 = 0; k0 < K; k0 += 64) {
        __syncthreads();                      // prev iteration's reads done
#pragma unroll
        for (int t = 0; t < 2; t++) {         // wave w stages rows w*16..w*16+15
            int rg = w * 16 + t * 8;
            gl_lds16(&A[(size_t)(m0 + rg + rsub) * K + k0 + c8 * 8], &sA[rg * 64]);
            gl_lds16(&Bt[(size_t)(n0 + rg + rsub) * K + k0 + c8 * 8], &sB[rg * 64]);
        }
        __syncthreads();                      // staging visible (vmcnt(0) implied)
#pragma unroll
        for (int ks = 0; ks < 64; ks += 32) {
            short8 af[2], bf[2];
#pragma unroll
            for (int i = 0; i < 2; i++)
                af[i] = *(const short8*)&sA[(wr * 32 + i * 16 + l15) * 64 + ks + quad * 8];
#pragma unroll
            for (int j = 0; j < 2; j++)
                bf[j] = *(const short8*)&sB[(wc * 32 + j * 16 + l15) * 64 + ks + quad * 8];
#pragma unroll
            for (int i = 0; i < 2; i++)
#pragma unroll
                for (int j = 0; j < 2; j++)
                    acc[i][j] = __builtin_amdgcn_mfma_f32_16x16x32_bf16(
                        af[i], bf[j], acc[i][j], 0, 0, 0);
        }
    }

    // C layout: row = quad*4+r, col = lane&15 (verified m89/m91)
#pragma unroll
    for (int i = 0; i < 2; i++)
#pragma unroll
        for (int j = 0; j < 2; j++)
#pragma unroll
            for (int r = 0; r < 4; r++) {
                int grow = m0 + wr * 32 + i * 16 + quad * 4 + r;
                int gcol = n0 + wc * 32 + j * 16 + l15;
                out_f[(size_t)grow * N + gcol] = acc[i][j][r] + bias[gcol];
            }
}

// ------- fused Q-projection + KV-projection + flash attention (v17) ---------
// grid = B*H = 1024 blocks, 512 threads (8 waves), 69.6 KB LDS -> 2 blocks/CU.
// v17 = v10 (verified 99/97.9us) + T5 setprio(1) around the proj and PV MFMA
// clusters. Regime: 2 independent blocks/CU at different phases (m191 attn
// regime, +4-7%), not m190's lockstep-null. No structural changes.
__global__ __launch_bounds__(512, 4) void fattn_kernel(
    const ushort_t* __restrict__ QA,   // qA  (b*128+i, 512) bf16
    const ushort_t* __restrict__ WQ,   // WqT (1024, 512) bf16, scale folded
    const ushort_t* __restrict__ KV,   // kvA (b*512+j, 256) bf16
    const ushort_t* __restrict__ W,    // WkvT (2048, 256) bf16
    ushort_t* __restrict__ O)          // (b*128+i, 1024)
{
    __shared__ ushort_t smem[34816];        // 69,632 B total
    ushort_t* sKV = smem;                   // main: 64x256 linear+swz (32 KB)
    ushort_t* sKc = smem + 16384;           // main: 64x72   ( 9.2 KB)
    ushort_t* sVt = smem + 20992;           // main: 64x72   ( 9.2 KB)
    ushort_t* sP  = smem + 25600;           // main: 8x16x72 (18.4 KB)
    ushort_t* sQ  = smem;                   // phase0: 128x128 linear+swz (32 KB)
    ushort_t* sW  = smem + 16384;           // phase0: 64x128 linear+swz (16 KB)

    // b-locality swizzle: xcd = bid&7 owns b in {8*xcd .. 8*xcd+7}
    const int bid  = blockIdx.x;
    const int xcd  = bid & 7;
    const int slot = bid >> 3;              // 0..127
    const int b = xcd * 8 + (slot & 7);
    const int h = slot >> 3;

    const int tid  = threadIdx.x;
    const int lane = tid & 63, w = tid >> 6;
    const int quad = lane >> 4, l15 = lane & 15;
    const int swz  = (l15 & 7) << 3;        // read-side XOR, ushort units (16B gran)

    ushort_t* sp = &sP[w * 1152];           // 16 x 72 per wave (private)

    // staging lane geometry
    const int rq = lane >> 4;               // sub-row 0..3 (4-row calls, 256B rows)
    const int gq = l15 * 8;                 // granule col, ushort units
    const int rh = lane >> 5;               // sub-row 0..1 (2-row calls, 512B rows)
    const int gk = (lane & 31) * 8;

    // ================= phase 0: q-projection for this (b,h) =================
    const ushort_t* qb = &QA[(size_t)b * 128 * 512];
    const ushort_t* wq = &WQ[(size_t)h * 64 * 512];
    floatx4 qacc[4];
#pragma unroll
    for (int nt = 0; nt < 4; nt++) qacc[nt] = (floatx4){0.f, 0.f, 0.f, 0.f};

    for (int kc = 0; kc < 4; kc++) {
        if (kc) __syncthreads();            // prev sub-chunk reads done
#pragma unroll
        for (int t = 0; t < 4; t++) {       // sQ: 16 rows/wave, 4 rows/call
            int rb = w * 16 + t * 4;        // wave-uniform LDS row base
            int srow = rb + rq;
            int scol = kc * 128 + (gq ^ ((srow & 7) << 3));
            gl_lds16(&qb[(size_t)srow * 512 + scol], &sQ[rb * 128]);
        }
#pragma unroll
        for (int t = 0; t < 2; t++) {       // sW: 8 rows/wave, 4 rows/call
            int rb = w * 8 + t * 4;
            int srow = rb + rq;
            int scol = kc * 128 + (gq ^ ((srow & 7) << 3));
            gl_lds16(&wq[(size_t)srow * 512 + scol], &sW[rb * 128]);
        }
        __syncthreads();                    // staging visible (vmcnt(0) implied)
#pragma unroll
        for (int ks = 0; ks < 4; ks++) {
            short8 af = *(const short8*)&sQ[(w * 16 + l15) * 128 + ((ks * 32 + quad * 8) ^ swz)];
#pragma unroll
            for (int nt = 0; nt < 4; nt++) {
                short8 bfr = *(const short8*)&sW[(nt * 16 + l15) * 128 + ((ks * 32 + quad * 8) ^ swz)];
                qacc[nt] = __builtin_amdgcn_mfma_f32_16x16x32_bf16(af, bfr, qacc[nt], 0, 0, 0);
            }
        }
    }
    __syncthreads();                        // all phase-0 LDS reads done

    const ushort_t* kvb = &KV[(size_t)b * 512 * 256];
    // issue kv chunk-0 staging NOW: covered by qh remap + wf loads below.
    // wave w stages its rows 8w..8w+7; 2 rows (1 KB) per call.
#define STAGE_KV(CH)                                                          \
    {                                                                         \
        _Pragma("unroll")                                                     \
        for (int t = 0; t < 4; t++) {                                         \
            int rloc = 8 * w + 2 * t;       /* wave-uniform LDS row base */   \
            int srow = rloc + rh;                                             \
            int scol = gk ^ ((srow & 7) << 3);                                \
            gl_lds16(&kvb[(size_t)((CH) * 64 + srow) * 256 + scol],           \
                     &sKV[rloc * 256]);                                       \
        }                                                                     \
    }
    STAGE_KV(0);

    // qh C-frags -> per-wave sp -> A-frags (lane remap through LDS)
#pragma unroll
    for (int nt = 0; nt < 4; nt++)
#pragma unroll
        for (int r = 0; r < 4; r++)
            sp[(quad * 4 + r) * 72 + nt * 16 + l15] = f2bf(qacc[nt][r]);
    short8 aq0 = *(const short8*)&sp[l15 * 72 + quad * 8];
    short8 aq1 = *(const short8*)&sp[l15 * 72 + 32 + quad * 8];

    // ---- W (kv) fragments in registers: wave w owns proj n-tile w ----
    short8 wf[8];
    {
        int n = w * 16 + l15;
        int grow = (n < 64) ? (h * 64 + n) : (1024 + h * 64 + (n - 64));
        const ushort_t* wp = &W[(size_t)grow * 256 + quad * 8];
#pragma unroll
        for (int ks = 0; ks < 8; ks++)
            wf[ks] = *(const short8*)(wp + ks * 32);
    }

    float lsum[4];
    floatx4 acc_o[4];
#pragma unroll
    for (int r = 0; r < 4; r++) lsum[r] = 0.f;
#pragma unroll
    for (int dt = 0; dt < 4; dt++) acc_o[dt] = (floatx4){0.f, 0.f, 0.f, 0.f};

    // ========================= main loop: 8 j-chunks ========================
    for (int ch = 0; ch < 8; ch++) {
        __syncthreads();                    // B1: vmcnt(0) drains prefetch; staging visible

        // ---- projection: pacc[jt] = kv_chunk(jt) @ W n-tile w, K=256 ----
        floatx4 pacc[4];
#pragma unroll
        for (int jt = 0; jt < 4; jt++) pacc[jt] = (floatx4){0.f, 0.f, 0.f, 0.f};
        __builtin_amdgcn_s_setprio(1);      // T5: favor this wave's MFMA burst
#pragma unroll
        for (int ks = 0; ks < 8; ks++) {
            short8 af[4];
#pragma unroll
            for (int jt = 0; jt < 4; jt++)
                af[jt] = *(const short8*)&sKV[(jt * 16 + l15) * 256 + ((ks * 32 + quad * 8) ^ swz)];
#pragma unroll
            for (int jt = 0; jt < 4; jt++)
                pacc[jt] = __builtin_amdgcn_mfma_f32_16x16x32_bf16(
                    af[jt], wf[ks], pacc[jt], 0, 0, 0);
        }
        __builtin_amdgcn_s_setprio(0);

        // ---- write Kc / Vc^T to LDS (C layout: row j = quad*4+r, col = l15) --
        if (w < 4) {
            int d = w * 16 + l15;
#pragma unroll
            for (int jt = 0; jt < 4; jt++)
#pragma unroll
                for (int r = 0; r < 4; r++)
                    sKc[(jt * 16 + quad * 4 + r) * 72 + d] = f2bf(pacc[jt][r]);
        } else {
            int d = (w - 4) * 16 + l15;
#pragma unroll
            for (int jt = 0; jt < 4; jt++) {
                ushortv4 p;
#pragma unroll
                for (int r = 0; r < 4; r++) p[r] = f2bf(pacc[jt][r]);
                *(ushortv4*)&sVt[d * 72 + jt * 16 + quad * 4] = p;
            }
        }
        __syncthreads();                    // B2: Kc/Vt visible; ALL proj sKV reads done

        // ---- issue next chunk's staging: hides under S+exp+PV ----
        if (ch < 7) STAGE_KV(ch + 1);

        // ---- S = Q * Kc^T (16 x 64), then P = exp(S) (no max needed) ----
#pragma unroll
        for (int jt = 0; jt < 4; jt++) {
            const ushort_t* kp = &sKc[(jt * 16 + l15) * 72 + quad * 8];
            short8 bk0 = *(const short8*)kp;
            short8 bk1 = *(const short8*)(kp + 32);
            floatx4 a = (floatx4){0.f, 0.f, 0.f, 0.f};
            a = __builtin_amdgcn_mfma_f32_16x16x32_bf16(aq0, bk0, a, 0, 0, 0);
            a = __builtin_amdgcn_mfma_f32_16x16x32_bf16(aq1, bk1, a, 0, 0, 0);
            ushortv4 pk;
#pragma unroll
            for (int r = 0; r < 4; r++) {
                float p = __expf(a[r]);
                lsum[r] += p;
                pk[r] = f2bf(p);
            }
#pragma unroll
            for (int r = 0; r < 4; r++)
                sp[(quad * 4 + r) * 72 + jt * 16 + l15] = pk[r];
        }

        // ---- O += P * V  (K = 64 j), per-wave private sp: no barrier ----
        __builtin_amdgcn_s_setprio(1);      // T5: PV MFMA cluster
#pragma unroll
        for (int kk = 0; kk < 2; kk++) {
            short8 ap = *(const short8*)&sp[l15 * 72 + kk * 32 + quad * 8];
#pragma unroll
            for (int dt = 0; dt < 4; dt++) {
                short8 bv = *(const short8*)&sVt[(dt * 16 + l15) * 72 + kk * 32 + quad * 8];
                acc_o[dt] = __builtin_amdgcn_mfma_f32_16x16x32_bf16(ap, bv, acc_o[dt], 0, 0, 0);
            }
        }
        __builtin_amdgcn_s_setprio(0);
    }

    // ---- final row-sum reduction (within 16-lane l15 groups) + write ----
#pragma unroll
    for (int r = 0; r < 4; r++) {
        float s = lsum[r];
#pragma unroll
        for (int off = 1; off < 16; off <<= 1) s += __shfl_xor(s, off);
        float inv = 1.0f / s;
        size_t rowo = (size_t)(b * 128 + w * 16 + quad * 4 + r) * 1024 + h * 64;
#pragma unroll
        for (int dt = 0; dt < 4; dt++)
            O[rowo + dt * 16 + l15] = f2bf(acc_o[dt][r] * inv);
    }
#undef STAGE_KV
}

// ---------------- launch ----------------
extern "C" void kernel_launch(void* const* d_in, const int* in_sizes, int n_in,
                              void* d_out, int out_size, void* d_ws, size_t ws_size,
                              hipStream_t stream) {
    const float* q   = (const float*)d_in[0];   // (64,128,512)
    const float* kv  = (const float*)d_in[1];   // (64,512,256)
    const float* Wq  = (const float*)d_in[2];   // (512,1024)
    const float* Wkv = (const float*)d_in[3];   // (256,2048)
    const float* Wo  = (const float*)d_in[4];   // (1024,512)
    const float* bo  = (const float*)d_in[5];   // (512,)
    float* out = (float*)d_out;

    char* ws = (char*)d_ws;
    ushort_t* qA    = (ushort_t*)(ws + 0);          //  8 MB  (8192 x 512)
    ushort_t* kvA   = (ushort_t*)(ws + 8388608);    // 16 MB  (32768 x 256)
    ushort_t* WqT   = (ushort_t*)(ws + 25165824);   //  1 MB  (1024 x 512)
    ushort_t* WkvT  = (ushort_t*)(ws + 26214400);   //  1 MB  (2048 x 256)
    ushort_t* WoT   = (ushort_t*)(ws + 27262976);   //  1 MB  (512 x 1024)
    ushort_t* attnO = (ushort_t*)(ws + 45088768);   // 16 MB  (8192 x 1024)

    // fused prep: 8-wide casts + tiled weight transposes, one launch
    hipLaunchKernelGGL(prep_kernel, dim3(6528), dim3(256), 0, stream,
                       q, kv, Wq, Wkv, Wo, qA, kvA, WqT, WkvT, WoT);

    // fused q-proj + kv-proj + attention (v10 + T5 setprio)
    hipLaunchKernelGGL(fattn_kernel, dim3(1024), dim3(512), 0, stream,
                       qA, WqT, kvA, WkvT, attnO);

    // out = attnO @ Wo + bo  -- 64x64 tiles, 1024 blocks = 4 blocks/CU
    hipLaunchKernelGGL(gemm_bt_kernel, dim3(1024), dim3(256), 0, stream,
                       attnO, WoT, 8192, 512, 1024, out, bo);
}